// Round 13
// baseline (465.742 us; speedup 1.0000x reference)
//
#include <hip/hip_runtime.h>
#include <hip/hip_bf16.h>

// Problem constants
#define B_  2
#define V_  4
#define Hin 480
#define Win 640
#define H2  240   // after conv1 (s2)
#define W2  320
#define H4  120   // after conv2 (s2)
#define W4  160
#define C1  32
#define C_  64
#define D_  5
#define NIMG 10  // B + B*V
#define HW4 (H4*W4)

// padded feature dims
#define P1H 242
#define P1W 322
#define P2H 122
#define P2W 162
// padded raw-input dims (for conv1 MFMA)
#define PIH 486
#define PIW 646

typedef __attribute__((ext_vector_type(8))) short short8;
typedef __attribute__((ext_vector_type(4))) float f32x4;

// ---------------- workspace layout (float offsets) ----------------
#define OFF_F1HI 0
#define OFF_F1LO 12467840
#define OFF_F2HI 24935680
#define OFF_F2LO 31260160
#define OFF_INHI 24935680
#define OFF_INLO 29645504
#define OFF_F3   0
#define OFF_SAMPW 12467840
#define OFF_SAMPM 15539840
#define OFF_GEOM 37584640
#define OFF_W1P  37584736   // ushort[2*6144]: hi then lo
#define OFF_W2P  37590880   // ushort[2*18432]: hi then lo
#define OFF_W3P  37609312   // ushort[2*36864]: hi then lo

// bijective XCD-aware block swizzle (m204): consecutive output tiles -> same XCD
__device__ __forceinline__ int swz8(int o, int n) {
    int x = o & 7, i = o >> 3, q = n >> 3, r = n & 7;
    return (x < r) ? (x * (q + 1) + i) : (r * (q + 1) + (x - r) * q + i);
}

// ---------------- pack conv2/conv3 weights into MFMA B-fragment order ----
__global__ void packw_kernel(const float* __restrict__ w, ushort* __restrict__ dst,
                             int CI, int NK, int lo_off) {
    int idx = blockIdx.x * 256 + threadIdx.x;
    int total = 4 * NK * 64 * 8;
    if (idx >= total) return;
    int j = idx & 7;
    int lane = (idx >> 3) & 63;
    int s = (idx >> 9) % NK;
    int t = idx / (NK * 512);
    int k = s * 32 + (lane >> 4) * 8 + j;
    int co = t * 16 + (lane & 15);
    int kyx = k / CI;
    int ci  = k % CI;
    int ky = kyx / 3, kx = kyx % 3;
    float val = w[((co * CI + ci) * 3 + ky) * 3 + kx];
    __hip_bfloat16 h = __float2bfloat16(val);
    float hf = __bfloat162float(h);
    __hip_bfloat16 l = __float2bfloat16(val - hf);
    dst[idx]          = *reinterpret_cast<ushort*>(&h);
    dst[lo_off + idx] = *reinterpret_cast<ushort*>(&l);
}

// ---------------- pack conv1 weights ----
__global__ void packw1_kernel(const float* __restrict__ w, ushort* __restrict__ dst) {
    int idx = blockIdx.x * 256 + threadIdx.x;
    if (idx >= 6144) return;
    int j = idx & 7;
    int lane = (idx >> 3) & 63;
    int s = (idx >> 9) % 6;
    int t = idx / 3072;
    int g = s * 4 + (lane >> 4);
    int co = t * 16 + (lane & 15);
    float val = 0.0f;
    if (g < 21 && j < 7) {
        int ci = g / 7, ky = g % 7;
        val = w[((co * 3 + ci) * 7 + ky) * 7 + j];
    }
    __hip_bfloat16 h = __float2bfloat16(val);
    float hf = __bfloat162float(h);
    __hip_bfloat16 l = __float2bfloat16(val - hf);
    dst[idx]        = *reinterpret_cast<ushort*>(&h);
    dst[6144 + idx] = *reinterpret_cast<ushort*>(&l);
}

// ---------------- pack raw images to padded NCHW bf16 hi/lo ----------------
__global__ void packin_kernel(const float* __restrict__ ref, const float* __restrict__ ngh,
                              ushort* __restrict__ ihi, ushort* __restrict__ ilo) {
    int idx = blockIdx.x * 256 + threadIdx.x;
    const int tot = NIMG * 3 * PIH * PIW;
    if (idx >= tot) return;
    int x = idx % PIW;
    int r = idx / PIW;
    int y = r % PIH;
    int rc = r / PIH;
    int ci = rc % 3;
    int n  = rc / 3;
    float val = 0.0f;
    int lx = x - 3, ly = y - 3;
    if (lx >= 0 && lx < Win && ly >= 0 && ly < Hin) {
        const float* img = (n < B_) ? (ref + ((size_t)n * 3 + ci) * Hin * Win)
                                    : (ngh + ((size_t)(n - B_) * 3 + ci) * Hin * Win);
        val = img[(size_t)ly * Win + lx];
    }
    __hip_bfloat16 h = __float2bfloat16(val);
    float hf = __bfloat162float(h);
    __hip_bfloat16 l = __float2bfloat16(val - hf);
    ihi[idx] = *reinterpret_cast<ushort*>(&h);
    ilo[idx] = *reinterpret_cast<ushort*>(&l);
}

// ---------------- zero padded-border cells of f1 and f2 ----------------
__global__ void zerob_kernel(ushort* __restrict__ f1hi, ushort* __restrict__ f1lo,
                             ushort* __restrict__ f2hi, ushort* __restrict__ f2lo) {
    const int F1B = 2 * P1W + 2 * (P1H - 2);
    const int F2B = 2 * P2W + 2 * (P2H - 2);
    const int f1tot = NIMG * F1B * C1;
    const int f2tot = NIMG * F2B * C_;
    int idx = blockIdx.x * 256 + threadIdx.x;
    if (idx < f1tot) {
        int c = idx & 31; int r = idx >> 5;
        int n = r / F1B; int bp = r % F1B;
        int y, x;
        if (bp < P1W)            { y = 0;        x = bp; }
        else if (bp < 2*P1W)     { y = P1H - 1;  x = bp - P1W; }
        else if (bp < 2*P1W + (P1H-2)) { y = bp - 2*P1W + 1;   x = 0; }
        else                     { y = bp - 2*P1W - (P1H-2) + 1; x = P1W - 1; }
        size_t o = (((size_t)n * P1H + y) * P1W + x) * C1 + c;
        f1hi[o] = 0; f1lo[o] = 0;
        return;
    }
    idx -= f1tot;
    if (idx < f2tot) {
        int c = idx & 63; int r = idx >> 6;
        int n = r / F2B; int bp = r % F2B;
        int y, x;
        if (bp < P2W)            { y = 0;        x = bp; }
        else if (bp < 2*P2W)     { y = P2H - 1;  x = bp - P2W; }
        else if (bp < 2*P2W + (P2H-2)) { y = bp - 2*P2W + 1;   x = 0; }
        else                     { y = bp - 2*P2W - (P2H-2) + 1; x = P2W - 1; }
        size_t o = (((size_t)n * P2H + y) * P2W + x) * C_ + c;
        f2hi[o] = 0; f2lo[o] = 0;
    }
}

// ---------------- geometry: A = K R Kinv, c = K t ----------------
__global__ void geom_kernel(const float* __restrict__ poses,
                            const float* __restrict__ Kmat,
                            float* __restrict__ geom) {
    int i = threadIdx.x;         // (b*V + v)
    if (i >= B_ * V_) return;
    int b = i / V_;
    const float* Kb = Kmat + b * 9;
    float k00=Kb[0],k01=Kb[1],k02=Kb[2];
    float k10=Kb[3],k11=Kb[4],k12=Kb[5];
    float k20=Kb[6],k21=Kb[7],k22=Kb[8];
    float det = k00*(k11*k22-k12*k21) - k01*(k10*k22-k12*k20) + k02*(k10*k21-k11*k20);
    float id = 1.0f / det;
    float ki[9];
    ki[0]=(k11*k22-k12*k21)*id; ki[1]=(k02*k21-k01*k22)*id; ki[2]=(k01*k12-k02*k11)*id;
    ki[3]=(k12*k20-k10*k22)*id; ki[4]=(k00*k22-k02*k20)*id; ki[5]=(k02*k10-k00*k12)*id;
    ki[6]=(k10*k21-k11*k20)*id; ki[7]=(k01*k20-k00*k21)*id; ki[8]=(k00*k11-k01*k10)*id;
    const float* P = poses + i * 16;
    float R[9] = {P[0],P[1],P[2], P[4],P[5],P[6], P[8],P[9],P[10]};
    float t[3] = {P[3],P[7],P[11]};
    float KR[9];
    for (int r = 0; r < 3; r++)
        for (int c = 0; c < 3; c++)
            KR[r*3+c] = Kb[r*3+0]*R[0*3+c] + Kb[r*3+1]*R[1*3+c] + Kb[r*3+2]*R[2*3+c];
    float* g = geom + i * 12;
    for (int r = 0; r < 3; r++)
        for (int c = 0; c < 3; c++)
            g[r*3+c] = KR[r*3+0]*ki[0*3+c] + KR[r*3+1]*ki[1*3+c] + KR[r*3+2]*ki[2*3+c];
    for (int r = 0; r < 3; r++)
        g[9+r] = Kb[r*3+0]*t[0] + Kb[r*3+1]*t[1] + Kb[r*3+2]*t[2];
}

// ---------------- conv1 MFMA: 3->32, 7x7, s2, p3, ReLU ----------
// wave: 32 px x 16 co; blockIdx.y = n*2 + co-chunk; grid (600, NIMG*2)
__global__ __launch_bounds__(256) void conv1_mfma(
        const ushort* __restrict__ ihi, const ushort* __restrict__ ilo,
        const ushort* __restrict__ w1p, const float* __restrict__ b1,
        ushort* __restrict__ f1hi, ushort* __restrict__ f1lo) {
    const int lane = threadIdx.x & 63;
    const int wv   = threadIdx.x >> 6;
    const int n    = blockIdx.y >> 1;
    const int tc   = blockIdx.y & 1;      // co-chunk (16 co)
    const int bx   = swz8(blockIdx.x, 600);
    const int px0  = bx * 128 + wv * 32;
    const int p0   = px0 + (lane & 15);
    const int p1   = p0 + 16;
    const int y0 = p0 / W2, x0 = p0 % W2;
    const int y1 = p1 / W2, x1 = p1 % W2;
    const int kg = lane >> 4;
    const ushort* ih = ihi + (size_t)n * 3 * PIH * PIW;
    const ushort* il = ilo + (size_t)n * 3 * PIH * PIW;

    f32x4 acc[2] = {};
#pragma unroll
    for (int s = 0; s < 6; s++) {
        const int g = s * 4 + kg;
        short8 a0h = {}, a0l = {}, a1h = {}, a1l = {};
        if (g < 21) {
            const int ci = g / 7, ky = g % 7;
            const size_t o0 = ((size_t)(ci * PIH + 2 * y0 + ky)) * PIW + 2 * x0;
            const size_t o1 = ((size_t)(ci * PIH + 2 * y1 + ky)) * PIW + 2 * x1;
            a0h = *reinterpret_cast<const short8*>(ih + o0);
            a0l = *reinterpret_cast<const short8*>(il + o0);
            a1h = *reinterpret_cast<const short8*>(ih + o1);
            a1l = *reinterpret_cast<const short8*>(il + o1);
        }
        const int widx = ((tc * 6 + s) * 64 + lane) * 8;
        short8 bhi = *reinterpret_cast<const short8*>(w1p + widx);
        short8 blo = *reinterpret_cast<const short8*>(w1p + 6144 + widx);
        acc[0] = __builtin_amdgcn_mfma_f32_16x16x32_bf16(a0h, bhi, acc[0], 0, 0, 0);
        acc[0] = __builtin_amdgcn_mfma_f32_16x16x32_bf16(a0h, blo, acc[0], 0, 0, 0);
        acc[0] = __builtin_amdgcn_mfma_f32_16x16x32_bf16(a0l, bhi, acc[0], 0, 0, 0);
        acc[1] = __builtin_amdgcn_mfma_f32_16x16x32_bf16(a1h, bhi, acc[1], 0, 0, 0);
        acc[1] = __builtin_amdgcn_mfma_f32_16x16x32_bf16(a1h, blo, acc[1], 0, 0, 0);
        acc[1] = __builtin_amdgcn_mfma_f32_16x16x32_bf16(a1l, bhi, acc[1], 0, 0, 0);
    }
    {
        const int co = tc * 16 + (lane & 15);
        const float bias = b1[co];
#pragma unroll
        for (int pt = 0; pt < 2; pt++) {
#pragma unroll
            for (int j = 0; j < 4; j++) {
                const int pr = px0 + pt * 16 + kg * 4 + j;
                const int oy = pr / W2, ox = pr % W2;
                float val = fmaxf(acc[pt][j] + bias, 0.0f);
                __hip_bfloat16 h = __float2bfloat16(val);
                float hf = __bfloat162float(h);
                __hip_bfloat16 l = __float2bfloat16(val - hf);
                const size_t o = (((size_t)n * P1H + (oy + 1)) * P1W + (ox + 1)) * C1 + co;
                f1hi[o] = *reinterpret_cast<ushort*>(&h);
                f1lo[o] = *reinterpret_cast<ushort*>(&l);
            }
        }
    }
}

// ---------------- conv2 MFMA: 32->64, 3x3, s2, p1, ReLU ----------------
// wave: 32 px x 32 co; blockIdx.y = n*2 + co-chunk; grid (150, NIMG*2)
__global__ __launch_bounds__(256) void conv2_mfma(
        const ushort* __restrict__ f1hi, const ushort* __restrict__ f1lo,
        const ushort* __restrict__ w2p, const float* __restrict__ b2,
        ushort* __restrict__ f2hi, ushort* __restrict__ f2lo) {
    const int lane = threadIdx.x & 63;
    const int wv   = threadIdx.x >> 6;
    const int n    = blockIdx.y >> 1;
    const int tc   = blockIdx.y & 1;      // co-chunk (32 co)
    const int bx   = swz8(blockIdx.x, 150);
    const int px0  = bx * 128 + wv * 32;
    const int p0   = px0 + (lane & 15);
    const int p1   = p0 + 16;
    const int y0 = p0 / W4, x0 = p0 % W4;
    const int y1 = p1 / W4, x1 = p1 % W4;
    const int kg = lane >> 4;                 // 0..3
    const ushort* ihi = f1hi + (size_t)n * P1H * P1W * C1;
    const ushort* ilo = f1lo + (size_t)n * P1H * P1W * C1;

    f32x4 acc[2][2] = {};
#pragma unroll
    for (int s = 0; s < 9; s++) {
        const int ky = s / 3, kx = s % 3;
        const int o0 = ((2 * y0 + ky) * P1W + (2 * x0 + kx)) * C1 + kg * 8;
        const int o1 = ((2 * y1 + ky) * P1W + (2 * x1 + kx)) * C1 + kg * 8;
        short8 a0h = *reinterpret_cast<const short8*>(ihi + o0);
        short8 a0l = *reinterpret_cast<const short8*>(ilo + o0);
        short8 a1h = *reinterpret_cast<const short8*>(ihi + o1);
        short8 a1l = *reinterpret_cast<const short8*>(ilo + o1);
#pragma unroll
        for (int t = 0; t < 2; t++) {
            const int tt = tc * 2 + t;
            const int widx = ((tt * 9 + s) * 64 + lane) * 8;
            short8 bhi = *reinterpret_cast<const short8*>(w2p + widx);
            short8 blo = *reinterpret_cast<const short8*>(w2p + 18432 + widx);
            acc[t][0] = __builtin_amdgcn_mfma_f32_16x16x32_bf16(a0h, bhi, acc[t][0], 0, 0, 0);
            acc[t][0] = __builtin_amdgcn_mfma_f32_16x16x32_bf16(a0h, blo, acc[t][0], 0, 0, 0);
            acc[t][0] = __builtin_amdgcn_mfma_f32_16x16x32_bf16(a0l, bhi, acc[t][0], 0, 0, 0);
            acc[t][1] = __builtin_amdgcn_mfma_f32_16x16x32_bf16(a1h, bhi, acc[t][1], 0, 0, 0);
            acc[t][1] = __builtin_amdgcn_mfma_f32_16x16x32_bf16(a1h, blo, acc[t][1], 0, 0, 0);
            acc[t][1] = __builtin_amdgcn_mfma_f32_16x16x32_bf16(a1l, bhi, acc[t][1], 0, 0, 0);
        }
    }
    ushort* ohi = f2hi + (size_t)n * P2H * P2W * C_;
    ushort* olo = f2lo + (size_t)n * P2H * P2W * C_;
#pragma unroll
    for (int t = 0; t < 2; t++) {
        const int co = (tc * 2 + t) * 16 + (lane & 15);
        const float bias = b2[co];
#pragma unroll
        for (int pt = 0; pt < 2; pt++) {
#pragma unroll
            for (int j = 0; j < 4; j++) {
                const int pr = px0 + pt * 16 + kg * 4 + j;
                const int yy = pr / W4, xx = pr % W4;
                float val = fmaxf(acc[t][pt][j] + bias, 0.0f);
                __hip_bfloat16 h = __float2bfloat16(val);
                float hf = __bfloat162float(h);
                __hip_bfloat16 l = __float2bfloat16(val - hf);
                const size_t o = (((size_t)(yy + 1)) * P2W + (xx + 1)) * C_ + co;
                ohi[o] = *reinterpret_cast<ushort*>(&h);
                olo[o] = *reinterpret_cast<ushort*>(&l);
            }
        }
    }
}

// ---------------- conv3 MFMA: 64->64, 3x3, s1, p1. out NHWC fp32 ----
// wave: 32 px x 32 co; blockIdx.y = n*2 + co-chunk; grid (150, NIMG*2)
__global__ __launch_bounds__(256) void conv3_mfma(
        const ushort* __restrict__ f2hi, const ushort* __restrict__ f2lo,
        const ushort* __restrict__ w3p, const float* __restrict__ b3,
        float* __restrict__ f3) {
    const int lane = threadIdx.x & 63;
    const int wv   = threadIdx.x >> 6;
    const int n    = blockIdx.y >> 1;
    const int tc   = blockIdx.y & 1;      // co-chunk (32 co)
    const int bx   = swz8(blockIdx.x, 150);
    const int px0  = bx * 128 + wv * 32;
    const int p0   = px0 + (lane & 15);
    const int p1   = p0 + 16;
    const int y0 = p0 / W4, x0 = p0 % W4;
    const int y1 = p1 / W4, x1 = p1 % W4;
    const int kg = lane >> 4;
    const ushort* ihi = f2hi + (size_t)n * P2H * P2W * C_;
    const ushort* ilo = f2lo + (size_t)n * P2H * P2W * C_;

    f32x4 acc[2][2] = {};
#pragma unroll
    for (int s = 0; s < 18; s++) {
        const int kyx = s >> 1;
        const int ky = kyx / 3, kx = kyx % 3;
        const int ci0 = (s & 1) * 32 + kg * 8;
        const int o0 = ((y0 + ky) * P2W + (x0 + kx)) * C_ + ci0;
        const int o1 = ((y1 + ky) * P2W + (x1 + kx)) * C_ + ci0;
        short8 a0h = *reinterpret_cast<const short8*>(ihi + o0);
        short8 a0l = *reinterpret_cast<const short8*>(ilo + o0);
        short8 a1h = *reinterpret_cast<const short8*>(ihi + o1);
        short8 a1l = *reinterpret_cast<const short8*>(ilo + o1);
#pragma unroll
        for (int t = 0; t < 2; t++) {
            const int tt = tc * 2 + t;
            const int widx = ((tt * 18 + s) * 64 + lane) * 8;
            short8 bhi = *reinterpret_cast<const short8*>(w3p + widx);
            short8 blo = *reinterpret_cast<const short8*>(w3p + 36864 + widx);
            acc[t][0] = __builtin_amdgcn_mfma_f32_16x16x32_bf16(a0h, bhi, acc[t][0], 0, 0, 0);
            acc[t][0] = __builtin_amdgcn_mfma_f32_16x16x32_bf16(a0h, blo, acc[t][0], 0, 0, 0);
            acc[t][0] = __builtin_amdgcn_mfma_f32_16x16x32_bf16(a0l, bhi, acc[t][0], 0, 0, 0);
            acc[t][1] = __builtin_amdgcn_mfma_f32_16x16x32_bf16(a1h, bhi, acc[t][1], 0, 0, 0);
            acc[t][1] = __builtin_amdgcn_mfma_f32_16x16x32_bf16(a1h, blo, acc[t][1], 0, 0, 0);
            acc[t][1] = __builtin_amdgcn_mfma_f32_16x16x32_bf16(a1l, bhi, acc[t][1], 0, 0, 0);
        }
    }
    float* op = f3 + (size_t)n * H4 * W4 * C_;
#pragma unroll
    for (int t = 0; t < 2; t++) {
        const int co = (tc * 2 + t) * 16 + (lane & 15);
        const float bias = b3[co];
#pragma unroll
        for (int pt = 0; pt < 2; pt++) {
#pragma unroll
            for (int j = 0; j < 4; j++) {
                const int pr = px0 + pt * 16 + kg * 4 + j;
                op[(size_t)pr * C_ + co] = acc[t][pt][j] + bias;
            }
        }
    }
}

// ---------------- sample geometry: one thread per (b,v,d,h,w) ----------------
// record: sw = {w00,w01,w10,w11}; sm = off00 | off10<<15 | mask<<30
__global__ void samp_kernel(const float* __restrict__ geom,
                            const float* __restrict__ dc,
                            const int*   __restrict__ valid,
                            f32x4* __restrict__ sw, int* __restrict__ sm) {
    int idx = blockIdx.x * 256 + threadIdx.x;
    if (idx >= B_ * V_ * D_ * HW4) return;
    int hw = idx % HW4;
    int r  = idx / HW4;
    int d = r % D_;  r /= D_;
    int v = r % V_;  int b = r / V_;
    int h = hw / W4, w = hw % W4;

    float dep = dc[((size_t)(b * D_ + d)) * HW4 + hw];
    const float* g = geom + (b * V_ + v) * 12;
    float px = dep * (g[0] * w + g[1] * h + g[2]) + g[9];
    float py = dep * (g[3] * w + g[4] * h + g[5]) + g[10];
    float pz = dep * (g[6] * w + g[7] * h + g[8]) + g[11];
    bool zok = pz > 0.001f;
    float zc = fmaxf(pz, 0.001f);
    float u  = px / zc;
    float vv = py / zc;
    bool inb = (u >= 0.f) && (u <= (float)(W4 - 1)) &&
               (vv >= 0.f) && (vv <= (float)(H4 - 1));
    bool m = zok && inb && (valid[b * V_ + v] != 0);

    f32x4 wgt = {0.f, 0.f, 0.f, 0.f};
    int rec = 0;
    if (m) {
        float u0f = floorf(u), v0f = floorf(vv);
        float du = u - u0f, dv = vv - v0f;
        int u0 = (int)u0f, v0 = (int)v0f;
        int off00 = v0 * W4 + u0;
        int off10 = min(v0 + 1, H4 - 1) * W4 + u0;
        wgt[0] = (1.f - du) * (1.f - dv);
        wgt[1] = du * (1.f - dv);
        wgt[2] = (1.f - du) * dv;
        wgt[3] = du * dv;
        rec = off00 | (off10 << 15) | (1 << 30);
    }
    sw[idx] = wgt;
    sm[idx] = rec;
}

// ---------------- warp + cost volume. 4 px per wave, float4 per lane ---------
// lane = g*16 + l : g = pixel-in-group (0..3), l = channel-quad (0..15)
__global__ __launch_bounds__(256) void warpcost_kernel(
        const float* __restrict__ feat,   // NHWC fp32, 10 imgs
        const f32x4* __restrict__ sw, const int* __restrict__ sm,
        float* __restrict__ out) {
    const int wave = threadIdx.x >> 6;
    const int lane = threadIdx.x & 63;
    const int g    = lane >> 4;
    const int l    = lane & 15;
    int pid = blockIdx.x * 16 + wave * 4 + g;   // 0 .. B*HW4-1 (groups never cross b)
    int b  = pid / HW4;
    int hw = pid % HW4;

    const f32x4 refc = *reinterpret_cast<const f32x4*>(
        feat + ((size_t)b * HW4 + hw) * C_ + l * 4);

    f32x4 accv[D_] = {};
    float den[D_]  = {0.f, 0.f, 0.f, 0.f, 0.f};

#pragma unroll
    for (int v = 0; v < V_; v++) {
        const float* fimg = feat + (size_t)(B_ + b * V_ + v) * HW4 * C_;
        const int rbase = ((b * V_ + v) * D_) * HW4 + hw;
#pragma unroll
        for (int d = 0; d < D_; d++) {
            int   rec = sm[rbase + d * HW4];
            f32x4 wv  = sw[rbase + d * HW4];
            int off00 = rec & 0x7FFF;
            int off10 = (rec >> 15) & 0x7FFF;
            const float* p0 = fimg + (size_t)off00 * C_ + l * 4;
            const float* p1 = fimg + (size_t)off10 * C_ + l * 4;
            f32x4 f00 = *reinterpret_cast<const f32x4*>(p0);
            f32x4 f01 = *reinterpret_cast<const f32x4*>(p0 + C_);
            f32x4 f10 = *reinterpret_cast<const f32x4*>(p1);
            f32x4 f11 = *reinterpret_cast<const f32x4*>(p1 + C_);
            accv[d] += f00 * wv[0] + f01 * wv[1] + f10 * wv[2] + f11 * wv[3];
            den[d]  += (float)((rec >> 30) & 1);
        }
    }

#pragma unroll
    for (int d = 0; d < D_; d++) {
        f32x4 pr = refc * accv[d];
        float s = (pr[0] + pr[1]) + (pr[2] + pr[3]);
        s += __shfl_xor(s, 1, 64);
        s += __shfl_xor(s, 2, 64);
        s += __shfl_xor(s, 4, 64);
        s += __shfl_xor(s, 8, 64);
        if (l == 0) {
            out[((size_t)b * D_ + d) * HW4 + hw] =
                (s * (1.0f / (float)C_)) / fmaxf(den[d], 1.0f);
        }
    }
}

extern "C" void kernel_launch(void* const* d_in, const int* in_sizes, int n_in,
                              void* d_out, int out_size, void* d_ws, size_t ws_size,
                              hipStream_t stream) {
    const float* ref_img  = (const float*)d_in[0];
    const float* ngh_img  = (const float*)d_in[1];
    const float* poses    = (const float*)d_in[2];
    const int*   is_valid = (const int*)  d_in[3];
    const float* K        = (const float*)d_in[4];
    const float* dc       = (const float*)d_in[5];
    const float* w1 = (const float*)d_in[6];
    const float* b1 = (const float*)d_in[7];
    const float* w2 = (const float*)d_in[8];
    const float* b2 = (const float*)d_in[9];
    const float* w3 = (const float*)d_in[10];
    const float* b3 = (const float*)d_in[11];
    float* out = (float*)d_out;

    float* ws = (float*)d_ws;
    ushort* f1hi = (ushort*)(ws + OFF_F1HI);
    ushort* f1lo = (ushort*)(ws + OFF_F1LO);
    ushort* f2hi = (ushort*)(ws + OFF_F2HI);
    ushort* f2lo = (ushort*)(ws + OFF_F2LO);
    ushort* inhi = (ushort*)(ws + OFF_INHI);  // aliases f2 region (dead after conv1)
    ushort* inlo = (ushort*)(ws + OFF_INLO);
    float*  f3   = ws + OFF_F3;               // overlaps f1hi (dead after conv2)
    f32x4*  sw   = (f32x4*)(ws + OFF_SAMPW);  // aliases f1lo (dead after conv2)
    int*    sm   = (int*)  (ws + OFF_SAMPM);
    float*  geom = ws + OFF_GEOM;
    ushort* w1p  = (ushort*)(ws + OFF_W1P);
    ushort* w2p  = (ushort*)(ws + OFF_W2P);
    ushort* w3p  = (ushort*)(ws + OFF_W3P);

    geom_kernel<<<1, 64, 0, stream>>>(poses, K, geom);
    packw1_kernel<<<24, 256, 0, stream>>>(w1, w1p);
    packw_kernel<<<(4*9*64*8 + 255)/256, 256, 0, stream>>>(w2, w2p, C1, 9, 18432);
    packw_kernel<<<(4*18*64*8 + 255)/256, 256, 0, stream>>>(w3, w3p, C_, 18, 36864);
    packin_kernel<<<(NIMG*3*PIH*PIW + 255)/256, 256, 0, stream>>>(ref_img, ngh_img, inhi, inlo);

    conv1_mfma<<<dim3(H2*W2/128, NIMG*2), 256, 0, stream>>>(inhi, inlo, w1p, b1, f1hi, f1lo);
    {
        const int ztot = NIMG*(2*P1W + 2*(P1H-2))*C1 + NIMG*(2*P2W + 2*(P2H-2))*C_;
        zerob_kernel<<<(ztot + 255)/256, 256, 0, stream>>>(f1hi, f1lo, f2hi, f2lo);
    }
    conv2_mfma<<<dim3(H4*W4/128, NIMG*2), 256, 0, stream>>>(f1hi, f1lo, w2p, b2, f2hi, f2lo);
    // samp writes into the f1lo alias -> must follow conv2 (stream-ordered)
    samp_kernel<<<(B_*V_*D_*HW4 + 255)/256, 256, 0, stream>>>(geom, dc, is_valid, sw, sm);
    conv3_mfma<<<dim3(H4*W4/128, NIMG*2), 256, 0, stream>>>(f2hi, f2lo, w3p, b3, f3);

    warpcost_kernel<<<(B_*HW4)/16, 256, 0, stream>>>(f3, sw, sm, out);
}

// Round 14
// 366.684 us; speedup vs baseline: 1.2701x; 1.2701x over previous
//
#include <hip/hip_runtime.h>
#include <hip/hip_bf16.h>

// Problem constants
#define B_  2
#define V_  4
#define Hin 480
#define Win 640
#define H2  240
#define W2  320
#define H4  120
#define W4  160
#define C1  32
#define C_  64
#define D_  5
#define NIMG 10
#define HW4 (H4*W4)

// padded feature dims
#define P1H 242
#define P1W 322
#define P2H 122
#define P2W 162
// padded raw-input dims
#define PIH 486
#define PIW 646

// channel-grouped planar feature layouts: per image [CG][PH][PW][8] (hi and lo)
#define F1IMG (4 * P1H * P1W * 8)   // 32ch -> 4 groups
#define F2IMG (8 * P2H * P2W * 8)   // 64ch -> 8 groups

typedef __attribute__((ext_vector_type(8))) short short8;
typedef __attribute__((ext_vector_type(4))) float f32x4;

// ---------------- workspace layout (float offsets) ----------------
#define OFF_F1HI 0
#define OFF_F1LO 12467840
#define OFF_F2HI 24935680
#define OFF_F2LO 31260160
#define OFF_INHI 24935680
#define OFF_INLO 29645504
#define OFF_F3   0
#define OFF_SAMPW 12467840
#define OFF_SAMPM 15539840
#define OFF_GEOM 37584640
#define OFF_W1P  37584736   // ushort[2*6144]: hi then lo
#define OFF_W2P  37590880   // ushort[2*18432]: hi then lo
#define OFF_W3P  37609312   // ushort[2*36864]: hi then lo

// bijective XCD-aware block swizzle (m204)
__device__ __forceinline__ int swz8(int o, int n) {
    int x = o & 7, i = o >> 3, q = n >> 3, r = n & 7;
    return (x < r) ? (x * (q + 1) + i) : (r * (q + 1) + (x - r) * q + i);
}

// ---------------- pack conv2/conv3 weights into MFMA B-fragment order ----
__global__ void packw_kernel(const float* __restrict__ w, ushort* __restrict__ dst,
                             int CI, int NK, int lo_off) {
    int idx = blockIdx.x * 256 + threadIdx.x;
    int total = 4 * NK * 64 * 8;
    if (idx >= total) return;
    int j = idx & 7;
    int lane = (idx >> 3) & 63;
    int s = (idx >> 9) % NK;
    int t = idx / (NK * 512);
    int k = s * 32 + (lane >> 4) * 8 + j;
    int co = t * 16 + (lane & 15);
    int kyx = k / CI;
    int ci  = k % CI;
    int ky = kyx / 3, kx = kyx % 3;
    float val = w[((co * CI + ci) * 3 + ky) * 3 + kx];
    __hip_bfloat16 h = __float2bfloat16(val);
    float hf = __bfloat162float(h);
    __hip_bfloat16 l = __float2bfloat16(val - hf);
    dst[idx]          = *reinterpret_cast<ushort*>(&h);
    dst[lo_off + idx] = *reinterpret_cast<ushort*>(&l);
}

// ---------------- pack conv1 weights ----
__global__ void packw1_kernel(const float* __restrict__ w, ushort* __restrict__ dst) {
    int idx = blockIdx.x * 256 + threadIdx.x;
    if (idx >= 6144) return;
    int j = idx & 7;
    int lane = (idx >> 3) & 63;
    int s = (idx >> 9) % 6;
    int t = idx / 3072;
    int g = s * 4 + (lane >> 4);
    int co = t * 16 + (lane & 15);
    float val = 0.0f;
    if (g < 21 && j < 7) {
        int ci = g / 7, ky = g % 7;
        val = w[((co * 3 + ci) * 7 + ky) * 7 + j];
    }
    __hip_bfloat16 h = __float2bfloat16(val);
    float hf = __bfloat162float(h);
    __hip_bfloat16 l = __float2bfloat16(val - hf);
    dst[idx]        = *reinterpret_cast<ushort*>(&h);
    dst[6144 + idx] = *reinterpret_cast<ushort*>(&l);
}

// ---------------- pack raw images to padded NCHW bf16 hi/lo ----------------
__global__ void packin_kernel(const float* __restrict__ ref, const float* __restrict__ ngh,
                              ushort* __restrict__ ihi, ushort* __restrict__ ilo) {
    int idx = blockIdx.x * 256 + threadIdx.x;
    const int tot = NIMG * 3 * PIH * PIW;
    if (idx >= tot) return;
    int x = idx % PIW;
    int r = idx / PIW;
    int y = r % PIH;
    int rc = r / PIH;
    int ci = rc % 3;
    int n  = rc / 3;
    float val = 0.0f;
    int lx = x - 3, ly = y - 3;
    if (lx >= 0 && lx < Win && ly >= 0 && ly < Hin) {
        const float* img = (n < B_) ? (ref + ((size_t)n * 3 + ci) * Hin * Win)
                                    : (ngh + ((size_t)(n - B_) * 3 + ci) * Hin * Win);
        val = img[(size_t)ly * Win + lx];
    }
    __hip_bfloat16 h = __float2bfloat16(val);
    float hf = __bfloat162float(h);
    __hip_bfloat16 l = __float2bfloat16(val - hf);
    ihi[idx] = *reinterpret_cast<ushort*>(&h);
    ilo[idx] = *reinterpret_cast<ushort*>(&l);
}

// ---------------- zero padded-border cells of f1 and f2 (grouped layout) ----
__global__ void zerob_kernel(ushort* __restrict__ f1hi, ushort* __restrict__ f1lo,
                             ushort* __restrict__ f2hi, ushort* __restrict__ f2lo) {
    const int F1B = 2 * P1W + 2 * (P1H - 2);
    const int F2B = 2 * P2W + 2 * (P2H - 2);
    const int f1tot = NIMG * F1B * C1;
    const int f2tot = NIMG * F2B * C_;
    int idx = blockIdx.x * 256 + threadIdx.x;
    if (idx < f1tot) {
        int c = idx & 31; int r = idx >> 5;
        int n = r / F1B; int bp = r % F1B;
        int y, x;
        if (bp < P1W)            { y = 0;        x = bp; }
        else if (bp < 2*P1W)     { y = P1H - 1;  x = bp - P1W; }
        else if (bp < 2*P1W + (P1H-2)) { y = bp - 2*P1W + 1;   x = 0; }
        else                     { y = bp - 2*P1W - (P1H-2) + 1; x = P1W - 1; }
        size_t o = (size_t)n * F1IMG + (((c >> 3) * (size_t)P1H + y) * P1W + x) * 8 + (c & 7);
        f1hi[o] = 0; f1lo[o] = 0;
        return;
    }
    idx -= f1tot;
    if (idx < f2tot) {
        int c = idx & 63; int r = idx >> 6;
        int n = r / F2B; int bp = r % F2B;
        int y, x;
        if (bp < P2W)            { y = 0;        x = bp; }
        else if (bp < 2*P2W)     { y = P2H - 1;  x = bp - P2W; }
        else if (bp < 2*P2W + (P2H-2)) { y = bp - 2*P2W + 1;   x = 0; }
        else                     { y = bp - 2*P2W - (P2H-2) + 1; x = P2W - 1; }
        size_t o = (size_t)n * F2IMG + (((c >> 3) * (size_t)P2H + y) * P2W + x) * 8 + (c & 7);
        f2hi[o] = 0; f2lo[o] = 0;
    }
}

// ---------------- geometry: A = K R Kinv, c = K t ----------------
__global__ void geom_kernel(const float* __restrict__ poses,
                            const float* __restrict__ Kmat,
                            float* __restrict__ geom) {
    int i = threadIdx.x;
    if (i >= B_ * V_) return;
    int b = i / V_;
    const float* Kb = Kmat + b * 9;
    float k00=Kb[0],k01=Kb[1],k02=Kb[2];
    float k10=Kb[3],k11=Kb[4],k12=Kb[5];
    float k20=Kb[6],k21=Kb[7],k22=Kb[8];
    float det = k00*(k11*k22-k12*k21) - k01*(k10*k22-k12*k20) + k02*(k10*k21-k11*k20);
    float id = 1.0f / det;
    float ki[9];
    ki[0]=(k11*k22-k12*k21)*id; ki[1]=(k02*k21-k01*k22)*id; ki[2]=(k01*k12-k02*k11)*id;
    ki[3]=(k12*k20-k10*k22)*id; ki[4]=(k00*k22-k02*k20)*id; ki[5]=(k02*k10-k00*k12)*id;
    ki[6]=(k10*k21-k11*k20)*id; ki[7]=(k01*k20-k00*k21)*id; ki[8]=(k00*k11-k01*k10)*id;
    const float* P = poses + i * 16;
    float R[9] = {P[0],P[1],P[2], P[4],P[5],P[6], P[8],P[9],P[10]};
    float t[3] = {P[3],P[7],P[11]};
    float KR[9];
    for (int r = 0; r < 3; r++)
        for (int c = 0; c < 3; c++)
            KR[r*3+c] = Kb[r*3+0]*R[0*3+c] + Kb[r*3+1]*R[1*3+c] + Kb[r*3+2]*R[2*3+c];
    float* g = geom + i * 12;
    for (int r = 0; r < 3; r++)
        for (int c = 0; c < 3; c++)
            g[r*3+c] = KR[r*3+0]*ki[0*3+c] + KR[r*3+1]*ki[1*3+c] + KR[r*3+2]*ki[2*3+c];
    for (int r = 0; r < 3; r++)
        g[9+r] = Kb[r*3+0]*t[0] + Kb[r*3+1]*t[1] + Kb[r*3+2]*t[2];
}

// ---------------- conv1 MFMA: 3->32, 7x7, s2, p3, ReLU. P=2 px-tiles ----------
// wave: 32 px x 32 co; grid (600, NIMG). writes grouped f1.
__global__ __launch_bounds__(256) void conv1_mfma(
        const ushort* __restrict__ ihi, const ushort* __restrict__ ilo,
        const ushort* __restrict__ w1p, const float* __restrict__ b1,
        ushort* __restrict__ f1hi, ushort* __restrict__ f1lo) {
    const int lane = threadIdx.x & 63;
    const int wv   = threadIdx.x >> 6;
    const int n    = blockIdx.y;
    const int bx   = swz8(blockIdx.x, 600);
    const int px0  = bx * 128 + wv * 32;
    const int p0   = px0 + (lane & 15);
    const int p1   = p0 + 16;
    const int y0 = p0 / W2, x0 = p0 % W2;
    const int y1 = p1 / W2, x1 = p1 % W2;
    const int kg = lane >> 4;
    const ushort* ih = ihi + (size_t)n * 3 * PIH * PIW;
    const ushort* il = ilo + (size_t)n * 3 * PIH * PIW;

    f32x4 acc[2][2] = {};
#pragma unroll
    for (int s = 0; s < 6; s++) {
        const int g = s * 4 + kg;
        short8 a0h = {}, a0l = {}, a1h = {}, a1l = {};
        if (g < 21) {
            const int ci = g / 7, ky = g % 7;
            const size_t o0 = ((size_t)(ci * PIH + 2 * y0 + ky)) * PIW + 2 * x0;
            const size_t o1 = ((size_t)(ci * PIH + 2 * y1 + ky)) * PIW + 2 * x1;
            a0h = *reinterpret_cast<const short8*>(ih + o0);
            a0l = *reinterpret_cast<const short8*>(il + o0);
            a1h = *reinterpret_cast<const short8*>(ih + o1);
            a1l = *reinterpret_cast<const short8*>(il + o1);
        }
#pragma unroll
        for (int t = 0; t < 2; t++) {
            const int widx = ((t * 6 + s) * 64 + lane) * 8;
            short8 bhi = *reinterpret_cast<const short8*>(w1p + widx);
            short8 blo = *reinterpret_cast<const short8*>(w1p + 6144 + widx);
            acc[t][0] = __builtin_amdgcn_mfma_f32_16x16x32_bf16(a0h, bhi, acc[t][0], 0, 0, 0);
            acc[t][0] = __builtin_amdgcn_mfma_f32_16x16x32_bf16(a0h, blo, acc[t][0], 0, 0, 0);
            acc[t][0] = __builtin_amdgcn_mfma_f32_16x16x32_bf16(a0l, bhi, acc[t][0], 0, 0, 0);
            acc[t][1] = __builtin_amdgcn_mfma_f32_16x16x32_bf16(a1h, bhi, acc[t][1], 0, 0, 0);
            acc[t][1] = __builtin_amdgcn_mfma_f32_16x16x32_bf16(a1h, blo, acc[t][1], 0, 0, 0);
            acc[t][1] = __builtin_amdgcn_mfma_f32_16x16x32_bf16(a1l, bhi, acc[t][1], 0, 0, 0);
        }
    }
#pragma unroll
    for (int t = 0; t < 2; t++) {
        const int co = t * 16 + (lane & 15);
        const int cg = co >> 3, c8 = co & 7;
        const float bias = b1[co];
#pragma unroll
        for (int pt = 0; pt < 2; pt++) {
#pragma unroll
            for (int j = 0; j < 4; j++) {
                const int pr = px0 + pt * 16 + kg * 4 + j;
                const int oy = pr / W2, ox = pr % W2;
                float val = fmaxf(acc[t][pt][j] + bias, 0.0f);
                __hip_bfloat16 h = __float2bfloat16(val);
                float hf = __bfloat162float(h);
                __hip_bfloat16 l = __float2bfloat16(val - hf);
                const size_t o = (size_t)n * F1IMG +
                    (((size_t)cg * P1H + (oy + 1)) * P1W + (ox + 1)) * 8 + c8;
                f1hi[o] = *reinterpret_cast<ushort*>(&h);
                f1lo[o] = *reinterpret_cast<ushort*>(&l);
            }
        }
    }
}

// ---------------- conv2 MFMA: 32->64, 3x3, s2, p1, ReLU. P=2 px-tiles --------
// wave: 32 px x 64 co; grid (150, NIMG). reads grouped f1, writes grouped f2.
__global__ __launch_bounds__(256) void conv2_mfma(
        const ushort* __restrict__ f1hi, const ushort* __restrict__ f1lo,
        const ushort* __restrict__ w2p, const float* __restrict__ b2,
        ushort* __restrict__ f2hi, ushort* __restrict__ f2lo) {
    const int lane = threadIdx.x & 63;
    const int wv   = threadIdx.x >> 6;
    const int n    = blockIdx.y;
    const int bx   = swz8(blockIdx.x, 150);
    const int px0  = bx * 128 + wv * 32;
    const int p0   = px0 + (lane & 15);
    const int p1   = p0 + 16;
    const int y0 = p0 / W4, x0 = p0 % W4;
    const int y1 = p1 / W4, x1 = p1 % W4;
    const int kg = lane >> 4;
    const ushort* ihi = f1hi + (size_t)n * F1IMG;
    const ushort* ilo = f1lo + (size_t)n * F1IMG;

    f32x4 acc[4][2] = {};
#pragma unroll
    for (int s = 0; s < 9; s++) {
        const int ky = s / 3, kx = s % 3;
        const int o0 = ((kg * P1H + (2 * y0 + ky)) * P1W + (2 * x0 + kx)) * 8;
        const int o1 = ((kg * P1H + (2 * y1 + ky)) * P1W + (2 * x1 + kx)) * 8;
        short8 a0h = *reinterpret_cast<const short8*>(ihi + o0);
        short8 a0l = *reinterpret_cast<const short8*>(ilo + o0);
        short8 a1h = *reinterpret_cast<const short8*>(ihi + o1);
        short8 a1l = *reinterpret_cast<const short8*>(ilo + o1);
#pragma unroll
        for (int t = 0; t < 4; t++) {
            const int widx = ((t * 9 + s) * 64 + lane) * 8;
            short8 bhi = *reinterpret_cast<const short8*>(w2p + widx);
            short8 blo = *reinterpret_cast<const short8*>(w2p + 18432 + widx);
            acc[t][0] = __builtin_amdgcn_mfma_f32_16x16x32_bf16(a0h, bhi, acc[t][0], 0, 0, 0);
            acc[t][0] = __builtin_amdgcn_mfma_f32_16x16x32_bf16(a0h, blo, acc[t][0], 0, 0, 0);
            acc[t][0] = __builtin_amdgcn_mfma_f32_16x16x32_bf16(a0l, bhi, acc[t][0], 0, 0, 0);
            acc[t][1] = __builtin_amdgcn_mfma_f32_16x16x32_bf16(a1h, bhi, acc[t][1], 0, 0, 0);
            acc[t][1] = __builtin_amdgcn_mfma_f32_16x16x32_bf16(a1h, blo, acc[t][1], 0, 0, 0);
            acc[t][1] = __builtin_amdgcn_mfma_f32_16x16x32_bf16(a1l, bhi, acc[t][1], 0, 0, 0);
        }
    }
    ushort* ohi = f2hi + (size_t)n * F2IMG;
    ushort* olo = f2lo + (size_t)n * F2IMG;
#pragma unroll
    for (int t = 0; t < 4; t++) {
        const int co = t * 16 + (lane & 15);
        const int cg = co >> 3, c8 = co & 7;
        const float bias = b2[co];
#pragma unroll
        for (int pt = 0; pt < 2; pt++) {
#pragma unroll
            for (int j = 0; j < 4; j++) {
                const int pr = px0 + pt * 16 + kg * 4 + j;
                const int yy = pr / W4, xx = pr % W4;
                float val = fmaxf(acc[t][pt][j] + bias, 0.0f);
                __hip_bfloat16 h = __float2bfloat16(val);
                float hf = __bfloat162float(h);
                __hip_bfloat16 l = __float2bfloat16(val - hf);
                const size_t o = (((size_t)cg * P2H + (yy + 1)) * P2W + (xx + 1)) * 8 + c8;
                ohi[o] = *reinterpret_cast<ushort*>(&h);
                olo[o] = *reinterpret_cast<ushort*>(&l);
            }
        }
    }
}

// ---------------- conv3 MFMA: 64->64, 3x3, s1, p1. out NHWC fp32 ----
// wave: 32 px x 64 co; grid (150, NIMG). reads grouped f2 (coalesced).
__global__ __launch_bounds__(256) void conv3_mfma(
        const ushort* __restrict__ f2hi, const ushort* __restrict__ f2lo,
        const ushort* __restrict__ w3p, const float* __restrict__ b3,
        float* __restrict__ f3) {
    const int lane = threadIdx.x & 63;
    const int wv   = threadIdx.x >> 6;
    const int n    = blockIdx.y;
    const int bx   = swz8(blockIdx.x, 150);
    const int px0  = bx * 128 + wv * 32;
    const int p0   = px0 + (lane & 15);
    const int p1   = p0 + 16;
    const int y0 = p0 / W4, x0 = p0 % W4;
    const int y1 = p1 / W4, x1 = p1 % W4;
    const int kg = lane >> 4;
    const ushort* ihi = f2hi + (size_t)n * F2IMG;
    const ushort* ilo = f2lo + (size_t)n * F2IMG;

    f32x4 acc[4][2] = {};
#pragma unroll
    for (int s = 0; s < 18; s++) {
        const int kyx = s >> 1;
        const int ky = kyx / 3, kx = kyx % 3;
        const int cg = (s & 1) * 4 + kg;
        const int o0 = ((cg * P2H + (y0 + ky)) * P2W + (x0 + kx)) * 8;
        const int o1 = ((cg * P2H + (y1 + ky)) * P2W + (x1 + kx)) * 8;
        short8 a0h = *reinterpret_cast<const short8*>(ihi + o0);
        short8 a0l = *reinterpret_cast<const short8*>(ilo + o0);
        short8 a1h = *reinterpret_cast<const short8*>(ihi + o1);
        short8 a1l = *reinterpret_cast<const short8*>(ilo + o1);
#pragma unroll
        for (int t = 0; t < 4; t++) {
            const int widx = ((t * 18 + s) * 64 + lane) * 8;
            short8 bhi = *reinterpret_cast<const short8*>(w3p + widx);
            short8 blo = *reinterpret_cast<const short8*>(w3p + 36864 + widx);
            acc[t][0] = __builtin_amdgcn_mfma_f32_16x16x32_bf16(a0h, bhi, acc[t][0], 0, 0, 0);
            acc[t][0] = __builtin_amdgcn_mfma_f32_16x16x32_bf16(a0h, blo, acc[t][0], 0, 0, 0);
            acc[t][0] = __builtin_amdgcn_mfma_f32_16x16x32_bf16(a0l, bhi, acc[t][0], 0, 0, 0);
            acc[t][1] = __builtin_amdgcn_mfma_f32_16x16x32_bf16(a1h, bhi, acc[t][1], 0, 0, 0);
            acc[t][1] = __builtin_amdgcn_mfma_f32_16x16x32_bf16(a1h, blo, acc[t][1], 0, 0, 0);
            acc[t][1] = __builtin_amdgcn_mfma_f32_16x16x32_bf16(a1l, bhi, acc[t][1], 0, 0, 0);
        }
    }
    float* op = f3 + (size_t)n * HW4 * C_;
#pragma unroll
    for (int t = 0; t < 4; t++) {
        const int co = t * 16 + (lane & 15);
        const float bias = b3[co];
#pragma unroll
        for (int pt = 0; pt < 2; pt++) {
#pragma unroll
            for (int j = 0; j < 4; j++) {
                const int pr = px0 + pt * 16 + kg * 4 + j;
                op[(size_t)pr * C_ + co] = acc[t][pt][j] + bias;
            }
        }
    }
}

// ---------------- sample geometry: one thread per (b,v,d,h,w) ----------------
__global__ void samp_kernel(const float* __restrict__ geom,
                            const float* __restrict__ dc,
                            const int*   __restrict__ valid,
                            f32x4* __restrict__ sw, int* __restrict__ sm) {
    int idx = blockIdx.x * 256 + threadIdx.x;
    if (idx >= B_ * V_ * D_ * HW4) return;
    int hw = idx % HW4;
    int r  = idx / HW4;
    int d = r % D_;  r /= D_;
    int v = r % V_;  int b = r / V_;
    int h = hw / W4, w = hw % W4;

    float dep = dc[((size_t)(b * D_ + d)) * HW4 + hw];
    const float* g = geom + (b * V_ + v) * 12;
    float px = dep * (g[0] * w + g[1] * h + g[2]) + g[9];
    float py = dep * (g[3] * w + g[4] * h + g[5]) + g[10];
    float pz = dep * (g[6] * w + g[7] * h + g[8]) + g[11];
    bool zok = pz > 0.001f;
    float zc = fmaxf(pz, 0.001f);
    float u  = px / zc;
    float vv = py / zc;
    bool inb = (u >= 0.f) && (u <= (float)(W4 - 1)) &&
               (vv >= 0.f) && (vv <= (float)(H4 - 1));
    bool m = zok && inb && (valid[b * V_ + v] != 0);

    f32x4 wgt = {0.f, 0.f, 0.f, 0.f};
    int rec = 0;
    if (m) {
        float u0f = floorf(u), v0f = floorf(vv);
        float du = u - u0f, dv = vv - v0f;
        int u0 = (int)u0f, v0 = (int)v0f;
        int off00 = v0 * W4 + u0;
        int off10 = min(v0 + 1, H4 - 1) * W4 + u0;
        wgt[0] = (1.f - du) * (1.f - dv);
        wgt[1] = du * (1.f - dv);
        wgt[2] = (1.f - du) * dv;
        wgt[3] = du * dv;
        rec = off00 | (off10 << 15) | (1 << 30);
    }
    sw[idx] = wgt;
    sm[idx] = rec;
}

// ---------------- warp + cost volume. 4 px per wave, float4 per lane ---------
__global__ __launch_bounds__(256) void warpcost_kernel(
        const float* __restrict__ feat,
        const f32x4* __restrict__ sw, const int* __restrict__ sm,
        float* __restrict__ out) {
    const int wave = threadIdx.x >> 6;
    const int lane = threadIdx.x & 63;
    const int g    = lane >> 4;
    const int l    = lane & 15;
    int pid = blockIdx.x * 16 + wave * 4 + g;
    int b  = pid / HW4;
    int hw = pid % HW4;

    const f32x4 refc = *reinterpret_cast<const f32x4*>(
        feat + ((size_t)b * HW4 + hw) * C_ + l * 4);

    f32x4 accv[D_] = {};
    float den[D_]  = {0.f, 0.f, 0.f, 0.f, 0.f};

#pragma unroll
    for (int v = 0; v < V_; v++) {
        const float* fimg = feat + (size_t)(B_ + b * V_ + v) * HW4 * C_;
        const int rbase = ((b * V_ + v) * D_) * HW4 + hw;
#pragma unroll
        for (int d = 0; d < D_; d++) {
            int   rec = sm[rbase + d * HW4];
            f32x4 wv  = sw[rbase + d * HW4];
            int off00 = rec & 0x7FFF;
            int off10 = (rec >> 15) & 0x7FFF;
            const float* p0 = fimg + (size_t)off00 * C_ + l * 4;
            const float* p1 = fimg + (size_t)off10 * C_ + l * 4;
            f32x4 f00 = *reinterpret_cast<const f32x4*>(p0);
            f32x4 f01 = *reinterpret_cast<const f32x4*>(p0 + C_);
            f32x4 f10 = *reinterpret_cast<const f32x4*>(p1);
            f32x4 f11 = *reinterpret_cast<const f32x4*>(p1 + C_);
            accv[d] += f00 * wv[0] + f01 * wv[1] + f10 * wv[2] + f11 * wv[3];
            den[d]  += (float)((rec >> 30) & 1);
        }
    }

#pragma unroll
    for (int d = 0; d < D_; d++) {
        f32x4 pr = refc * accv[d];
        float s = (pr[0] + pr[1]) + (pr[2] + pr[3]);
        s += __shfl_xor(s, 1, 64);
        s += __shfl_xor(s, 2, 64);
        s += __shfl_xor(s, 4, 64);
        s += __shfl_xor(s, 8, 64);
        if (l == 0) {
            out[((size_t)b * D_ + d) * HW4 + hw] =
                (s * (1.0f / (float)C_)) / fmaxf(den[d], 1.0f);
        }
    }
}

extern "C" void kernel_launch(void* const* d_in, const int* in_sizes, int n_in,
                              void* d_out, int out_size, void* d_ws, size_t ws_size,
                              hipStream_t stream) {
    const float* ref_img  = (const float*)d_in[0];
    const float* ngh_img  = (const float*)d_in[1];
    const float* poses    = (const float*)d_in[2];
    const int*   is_valid = (const int*)  d_in[3];
    const float* K        = (const float*)d_in[4];
    const float* dc       = (const float*)d_in[5];
    const float* w1 = (const float*)d_in[6];
    const float* b1 = (const float*)d_in[7];
    const float* w2 = (const float*)d_in[8];
    const float* b2 = (const float*)d_in[9];
    const float* w3 = (const float*)d_in[10];
    const float* b3 = (const float*)d_in[11];
    float* out = (float*)d_out;

    float* ws = (float*)d_ws;
    ushort* f1hi = (ushort*)(ws + OFF_F1HI);
    ushort* f1lo = (ushort*)(ws + OFF_F1LO);
    ushort* f2hi = (ushort*)(ws + OFF_F2HI);
    ushort* f2lo = (ushort*)(ws + OFF_F2LO);
    ushort* inhi = (ushort*)(ws + OFF_INHI);  // aliases f2 region (dead after conv1)
    ushort* inlo = (ushort*)(ws + OFF_INLO);
    float*  f3   = ws + OFF_F3;               // overlaps f1hi (dead after conv2)
    f32x4*  sw   = (f32x4*)(ws + OFF_SAMPW);  // aliases f1lo (dead after conv2)
    int*    sm   = (int*)  (ws + OFF_SAMPM);
    float*  geom = ws + OFF_GEOM;
    ushort* w1p  = (ushort*)(ws + OFF_W1P);
    ushort* w2p  = (ushort*)(ws + OFF_W2P);
    ushort* w3p  = (ushort*)(ws + OFF_W3P);

    geom_kernel<<<1, 64, 0, stream>>>(poses, K, geom);
    packw1_kernel<<<24, 256, 0, stream>>>(w1, w1p);
    packw_kernel<<<(4*9*64*8 + 255)/256, 256, 0, stream>>>(w2, w2p, C1, 9, 18432);
    packw_kernel<<<(4*18*64*8 + 255)/256, 256, 0, stream>>>(w3, w3p, C_, 18, 36864);
    packin_kernel<<<(NIMG*3*PIH*PIW + 255)/256, 256, 0, stream>>>(ref_img, ngh_img, inhi, inlo);

    conv1_mfma<<<dim3(H2*W2/128, NIMG), 256, 0, stream>>>(inhi, inlo, w1p, b1, f1hi, f1lo);
    {
        const int ztot = NIMG*(2*P1W + 2*(P1H-2))*C1 + NIMG*(2*P2W + 2*(P2H-2))*C_;
        zerob_kernel<<<(ztot + 255)/256, 256, 0, stream>>>(f1hi, f1lo, f2hi, f2lo);
    }
    conv2_mfma<<<dim3(H4*W4/128, NIMG), 256, 0, stream>>>(f1hi, f1lo, w2p, b2, f2hi, f2lo);
    // samp writes into the f1lo alias -> must follow conv2 (stream-ordered)
    samp_kernel<<<(B_*V_*D_*HW4 + 255)/256, 256, 0, stream>>>(geom, dc, is_valid, sw, sm);
    conv3_mfma<<<dim3(H4*W4/128, NIMG), 256, 0, stream>>>(f2hi, f2lo, w3p, b3, f3);

    warpcost_kernel<<<(B_*HW4)/16, 256, 0, stream>>>(f3, sw, sm, out);
}